// Round 10
// baseline (10497.037 us; speedup 1.0000x reference)
//
#include <hip/hip_runtime.h>

// Problem dims (hardcoded per reference)
constexpr int kB   = 64;    // batch
constexpr int kM   = 32;    // rows
constexpr int kN   = 32;    // cols
constexpr int kD   = 256;   // input/vocab dim
constexpr int kH   = 256;   // hidden
constexpr int kG5  = 1280;  // 5H
constexpr int kGP  = 32 * 64 * 1280;   // gates plane (floats)
constexpr int kCP  = 32 * 64 * 256;    // c plane (floats)

typedef __attribute__((ext_vector_type(8)))  short bf16x8;
typedef __attribute__((ext_vector_type(16))) float f32x16;

__device__ __forceinline__ float bu2f(unsigned short u) {
    return __uint_as_float(((unsigned)u) << 16);
}
__device__ __forceinline__ unsigned short f2bu(float f) {
    unsigned u = __float_as_uint(f);
    return (unsigned short)((u + 0x7FFF + ((u >> 16) & 1)) >> 16);   // RNE
}
__device__ __forceinline__ void split1(float a, unsigned short& hi, unsigned short& lo) {
    hi = f2bu(a);
    lo = f2bu(a - bu2f(hi));     // |residual after lo| <= 2^-18 |a|
}
__device__ __forceinline__ float sigm(float x) { return 1.f / (1.f + expf(-x)); }

// ---------------------------------------------------------------------------
// Prep 1: Wg (fp32 [768][1280]) -> MFMA-B-frag bf16 hi/lo panels.
// ---------------------------------------------------------------------------
__global__ void prep_w(const float* __restrict__ Wg,
                       unsigned short* __restrict__ whi,
                       unsigned short* __restrict__ wlo) {
    const int t = blockIdx.x * 256 + threadIdx.x;     // 0..122879
    const int lane = t & 63;
    const int rest = t >> 6;
    const int s = rest % 48;
    const int ntile = rest / 48;
    const int n = ntile * 32 + (lane & 31);
    const int kb = s * 16 + (lane >> 5) * 8;
    unsigned short h8[8], l8[8];
    #pragma unroll
    for (int j = 0; j < 8; ++j) {
        const float a = Wg[(size_t)(kb + j) * kG5 + n];
        split1(a, h8[j], l8[j]);
    }
    *(bf16x8*)(whi + (size_t)t * 8) = *(const bf16x8*)h8;
    *(bf16x8*)(wlo + (size_t)t * 8) = *(const bf16x8*)l8;
}

// Prep 2: W_head -> B-frag bf16 hi/lo (8 ntiles x 16 chunks)
__global__ void prep_wh(const float* __restrict__ Wh,
                        unsigned short* __restrict__ whh,
                        unsigned short* __restrict__ whl) {
    const int t = blockIdx.x * 256 + threadIdx.x;     // 0..8191
    const int lane = t & 63;
    const int rest = t >> 6;
    const int kc = rest & 15;
    const int nt = rest >> 4;
    const int n = nt * 32 + (lane & 31);
    const int kb = kc * 16 + (lane >> 5) * 8;
    unsigned short h8[8], l8[8];
    #pragma unroll
    for (int j = 0; j < 8; ++j) {
        const float a = Wh[(size_t)(kb + j) * kD + n];
        split1(a, h8[j], l8[j]);
    }
    *(bf16x8*)(whh + (size_t)t * 8) = *(const bf16x8*)h8;
    *(bf16x8*)(whl + (size_t)t * 8) = *(const bf16x8*)l8;
}

// Prep 3: h_init -> A-frag layout [kh][lane][8]
__global__ void prep_h0f(const float* __restrict__ hinit,
                         unsigned short* __restrict__ h0fh,
                         unsigned short* __restrict__ h0fl) {
    const int idx = blockIdx.x * 256 + threadIdx.x;   // 0..1023
    const int lane = idx & 63;
    const int kh = idx >> 6;
    const int k0 = kh * 16 + (lane >> 5) * 8;
    unsigned short h8[8], l8[8];
    #pragma unroll
    for (int j = 0; j < 8; ++j) split1(hinit[k0 + j], h8[j], l8[j]);
    *(bf16x8*)(h0fh + (size_t)idx * 8) = *(const bf16x8*)h8;
    *(bf16x8*)(h0fl + (size_t)idx * 8) = *(const bf16x8*)l8;
}

// Prep 4: pre-split x into A-frag bf16 hi/lo panels, per (cell,mt).
__global__ void prep_x(const float* __restrict__ x,
                       unsigned short* __restrict__ xfh,
                       unsigned short* __restrict__ xfl) {
    const int t = blockIdx.x * 256 + threadIdx.x;     // 0..2097151
    const int kq   = t & 31;
    const int b    = (t >> 5) & 63;
    const int cell = t >> 11;
    const float* src = x + (((size_t)b * 1024 + cell) * kD + kq * 8);
    unsigned short h8[8], l8[8];
    #pragma unroll
    for (int j = 0; j < 8; ++j) split1(src[j], h8[j], l8[j]);
    const int mt = b >> 5, kh = kq >> 1;
    const int l  = (b & 31) + 32 * (kq & 1);
    const size_t dst = ((((size_t)cell * 2 + mt) * 16 + kh) * 64 + l) * 8;
    *(bf16x8*)(xfh + dst) = *(const bf16x8*)h8;
    *(bf16x8*)(xfl + dst) = *(const bf16x8*)l8;
}

// ---------------------------------------------------------------------------
// Compute the full h of neighbor cell (ip,jp) (diag d-1) into LDS frag arrays,
// from gates[d-1] + c[d-2]. Thread: batch b=tid>>2, quarter q=tid&3 (64 units).
// Trick: pass1 stores raw cell_v BITS split across sfh/sfl (exact roundtrip),
// pass2 reads own slots back, applies LN+tanh, overwrites with h hi/lo split.
// writer (block-uniform): persists c and packed-h (out-overlay, head input).
// ---------------------------------------------------------------------------
__device__ __forceinline__
void cell_into_lds(int tid, int ip, int jp, bool writer,
                   const float* __restrict__ gprev,
                   const float* __restrict__ cprev,
                   float* __restrict__ ccur,
                   const float* __restrict__ bg,
                   const float* __restrict__ lns,
                   const float* __restrict__ lnb,
                   unsigned* __restrict__ outp,
                   unsigned short* sfh, unsigned short* sfl) {
    const int b  = tid >> 2;
    const int q  = tid & 3;
    const int u0 = q * 64;
    const int mt = b >> 5;
    const float* grow  = gprev + ((size_t)ip * kB + b) * kG5;
    const float* clrow = (jp > 0) ? cprev + ((size_t)ip * kB + b) * kH : nullptr;
    const float* curow = (ip > 0) ? cprev + ((size_t)(ip - 1) * kB + b) * kH : nullptr;
    float* crow = ccur + ((size_t)ip * kB + b) * kH;

    float s = 0.f, s2 = 0.f;
    for (int k4 = 0; k4 < 16; ++k4) {
        const int u = u0 + k4 * 4;
        const float4 g0 = *(const float4*)(grow + u);
        const float4 g1 = *(const float4*)(grow + kH + u);
        const float4 g2 = *(const float4*)(grow + 2 * kH + u);
        const float4 g4 = *(const float4*)(grow + 4 * kH + u);
        const float4 b0 = *(const float4*)(bg + u);
        const float4 b1 = *(const float4*)(bg + kH + u);
        const float4 b2 = *(const float4*)(bg + 2 * kH + u);
        const float4 b4 = *(const float4*)(bg + 4 * kH + u);
        float4 cl4 = make_float4(0.f, 0.f, 0.f, 0.f);
        float4 cu4 = make_float4(0.f, 0.f, 0.f, 0.f);
        if (clrow) cl4 = *(const float4*)(clrow + u);
        if (curow) cu4 = *(const float4*)(curow + u);
        #pragma unroll
        for (int e = 0; e < 4; ++e) {
            const float fc = ((const float*)&g0)[e] + ((const float*)&b0)[e];
            const float fr = ((const float*)&g1)[e] + ((const float*)&b1)[e];
            const float ig = ((const float*)&g2)[e] + ((const float*)&b2)[e];
            const float gg = ((const float*)&g4)[e] + ((const float*)&b4)[e];
            const float cl = ((const float*)&cl4)[e];
            const float cu = ((const float*)&cu4)[e];
            const float cv = sigm(fc) * cl + sigm(fr) * cu + sigm(ig) * tanhf(gg);
            s += cv; s2 += cv * cv;
            const int u_ = u + e;
            const int kh = u_ >> 4;
            const int ln = (b & 31) + 32 * ((u_ >> 3) & 1);
            const int el = u_ & 7;
            const int slot = ((mt * 16 + kh) * 64 + ln) * 8 + el;
            const unsigned bits = __float_as_uint(cv);
            sfh[slot] = (unsigned short)(bits >> 16);
            sfl[slot] = (unsigned short)(bits & 0xffffu);
            if (writer) crow[u_] = cv;
        }
    }
    // 4-lane group reduce (threads b*4+q are adjacent lanes)
    s  += __shfl_xor(s, 1, 64);  s  += __shfl_xor(s, 2, 64);
    s2 += __shfl_xor(s2, 1, 64); s2 += __shfl_xor(s2, 2, 64);
    const float mu   = s * (1.f / kH);
    const float var  = s2 * (1.f / kH) - mu * mu;
    const float rstd = rsqrtf(var + 1e-6f);

    const size_t R = ((size_t)b * kM + ip) * kN + jp;
    const int t32 = (int)(R >> 5);
    for (int k4 = 0; k4 < 16; ++k4) {
        const int u = u0 + k4 * 4;
        const float4 g3 = *(const float4*)(grow + 3 * kH + u);
        const float4 b3 = *(const float4*)(bg + 3 * kH + u);
        const float4 ls = *(const float4*)(lns + u);
        const float4 lb = *(const float4*)(lnb + u);
        #pragma unroll
        for (int e = 0; e < 4; ++e) {
            const int u_ = u + e;
            const int kh = u_ >> 4;
            const int ln = (b & 31) + 32 * ((u_ >> 3) & 1);
            const int el = u_ & 7;
            const int slot = ((mt * 16 + kh) * 64 + ln) * 8 + el;
            const unsigned bits = ((unsigned)sfh[slot] << 16) | (unsigned)sfl[slot];
            const float cv = __uint_as_float(bits);
            const float og = ((const float*)&g3)[e] + ((const float*)&b3)[e];
            const float hv = sigm(og) * tanhf((cv - mu) * rstd * ((const float*)&ls)[e]
                                              + ((const float*)&lb)[e]);
            unsigned short hb, lbb;
            split1(hv, hb, lbb);
            sfh[slot] = hb; sfl[slot] = lbb;
            if (writer) {
                const int lp = ((int)R & 31) + 32 * ((u_ >> 3) & 1);
                outp[(((size_t)t32 * 16 + kh) * 64 + lp) * 8 + el] =
                    (unsigned)hb | ((unsigned)lbb << 16);
            }
        }
    }
}

// Copy h_init frags (b-independent) into both mt halves of the LDS frag arrays.
__device__ __forceinline__
void h0_into_lds(int tid,
                 const unsigned short* __restrict__ h0fh,
                 const unsigned short* __restrict__ h0fl,
                 unsigned short* sfh, unsigned short* sfl) {
    #pragma unroll
    for (int rr = 0; rr < 8; ++rr) {
        const int row = tid * 8 + rr;          // 0..2047
        const int src = row & 1023;            // kh*64+lane (mt-independent)
        *(bf16x8*)(sfh + (size_t)row * 8) = *(const bf16x8*)(h0fh + (size_t)src * 8);
        *(bf16x8*)(sfl + (size_t)row * 8) = *(const bf16x8*)(h0fl + (size_t)src * 8);
    }
}

// ---------------------------------------------------------------------------
// Fused per-diagonal kernel: ONE dispatch per diagonal (round-8 lesson: fixed
// ~11us/dispatch dominates; internals don't). Block = (cell, nc of 20).
// Phase A: recompute h_l = cell(i,j-1) of diag d-1 into LDS (or h0 copy).
// MFMA x(0-15)+h_l(16-31). Phase B: recompute h_u = cell(i-1,j) into LDS.
// MFMA h_u(32-47). Epilogue -> gates[d&1]. Designated blocks persist c and
// packed-h (out-overlay, exactly-once coverage: left-write for j'<=30 cells,
// up-write (nc==1 && j==31) for j'==31 cells). Gates double-buffered by
// diagonal parity so reads(d-1) never race writes(d).
// ---------------------------------------------------------------------------
__global__ __launch_bounds__(256)
void gate_fused(int d,
                const unsigned short* __restrict__ xfh,
                const unsigned short* __restrict__ xfl,
                const unsigned short* __restrict__ whi,
                const unsigned short* __restrict__ wlo,
                const unsigned short* __restrict__ h0fh,
                const unsigned short* __restrict__ h0fl,
                const float* __restrict__ gprev,
                float* __restrict__ gcur,
                const float* __restrict__ cprev,
                float* __restrict__ ccur,
                const float* __restrict__ bg,
                const float* __restrict__ lns,
                const float* __restrict__ lnb,
                unsigned* __restrict__ outp) {
    __shared__ __align__(16) unsigned short sfh[16384];   // 32 KB
    __shared__ __align__(16) unsigned short sfl[16384];   // 32 KB
    const int tid = threadIdx.x;
    const int ilo = max(0, d - (kN - 1));
    const int cell = blockIdx.x / 20;
    const int nc   = blockIdx.x % 20;
    const int i = ilo + cell;
    const int j = d - i;

    // ---- phase A: h_l ----
    if (j == 0) h0_into_lds(tid, h0fh, h0fl, sfh, sfl);
    else cell_into_lds(tid, i, j - 1, nc == 0, gprev, cprev, ccur,
                       bg, lns, lnb, outp, sfh, sfl);
    __syncthreads();

    const int w = tid >> 6, lane = tid & 63;
    const int ln31 = lane & 31, ln5 = lane >> 5;
    const int mt = w & 1;
    const int ntile = nc * 2 + (w >> 1);
    const int cl_ = i * kN + j;

    f32x16 acc;
    #pragma unroll
    for (int r = 0; r < 16; ++r) acc[r] = 0.f;

    const unsigned short* wph = whi + ((size_t)ntile * 3072 + lane) * 8;
    const unsigned short* wpl = wlo + ((size_t)ntile * 3072 + lane) * 8;
    const unsigned short* xph = xfh + (((size_t)cl_ * 2 + mt) * 1024 + lane) * 8;
    const unsigned short* xpl = xfl + (((size_t)cl_ * 2 + mt) * 1024 + lane) * 8;
    const unsigned short* lfh = sfh + ((size_t)(mt * 16) * 64 + lane) * 8;
    const unsigned short* lfl = sfl + ((size_t)(mt * 16) * 64 + lane) * 8;

#define CHUNK3(AH, AL, WC)                                                      \
    {                                                                           \
        const bf16x8 ah = *(const bf16x8*)(AH);                                 \
        const bf16x8 al = *(const bf16x8*)(AL);                                 \
        const bf16x8 wh = *(const bf16x8*)(wph + (size_t)(WC) * 512);           \
        const bf16x8 wl = *(const bf16x8*)(wpl + (size_t)(WC) * 512);           \
        acc = __builtin_amdgcn_mfma_f32_32x32x16_bf16(ah, wh, acc, 0, 0, 0);    \
        acc = __builtin_amdgcn_mfma_f32_32x32x16_bf16(ah, wl, acc, 0, 0, 0);    \
        acc = __builtin_amdgcn_mfma_f32_32x32x16_bf16(al, wh, acc, 0, 0, 0);    \
    }

    // ---- MFMA: x chunks 0..15 (window-synced, round-6 verified pattern) ----
    #pragma unroll
    for (int kw = 0; kw < 4; ++kw) {
        __syncthreads();
        #pragma unroll
        for (int k4 = 0; k4 < 4; ++k4) {
            const int kh = kw * 4 + k4;
            CHUNK3(xph + (size_t)kh * 512, xpl + (size_t)kh * 512, kh)
        }
    }
    // ---- MFMA: h_l chunks (W 16..31), A from LDS ----
    #pragma unroll
    for (int kw = 0; kw < 4; ++kw) {
        __syncthreads();
        #pragma unroll
        for (int k4 = 0; k4 < 4; ++k4) {
            const int kh = kw * 4 + k4;
            CHUNK3(lfh + (size_t)kh * 512, lfl + (size_t)kh * 512, 16 + kh)
        }
    }
    __syncthreads();   // all h_l reads done before overwrite

    // ---- phase B: h_u ----
    if (i == 0) h0_into_lds(tid, h0fh, h0fl, sfh, sfl);
    else cell_into_lds(tid, i - 1, j, (nc == 1) && (j == 31), gprev, cprev, ccur,
                       bg, lns, lnb, outp, sfh, sfl);
    __syncthreads();

    // ---- MFMA: h_u chunks (W 32..47) ----
    #pragma unroll
    for (int kw = 0; kw < 4; ++kw) {
        __syncthreads();
        #pragma unroll
        for (int k4 = 0; k4 < 4; ++k4) {
            const int kh = kw * 4 + k4;
            CHUNK3(lfh + (size_t)kh * 512, lfl + (size_t)kh * 512, 32 + kh)
        }
    }
#undef CHUNK3

    // ---- epilogue: C/D layout col=lane&31, row=(r&3)+8*(r>>2)+4*(lane>>5) ----
    const int col = ntile * 32 + ln31;
    #pragma unroll
    for (int r = 0; r < 16; ++r) {
        const int mrow = (r & 3) + 8 * (r >> 2) + 4 * ln5;
        const int bb = mt * 32 + mrow;
        gcur[((size_t)i * kB + bb) * kG5 + col] = acc[r];
    }
}

// ---------------------------------------------------------------------------
// Trailing cell for diag 62 (cell (31,31)): write packed-h overlay only.
// ---------------------------------------------------------------------------
__global__ __launch_bounds__(256)
void cell_tail(const float* __restrict__ gate0,   // gates plane 0 (d=62)
               const float* __restrict__ cprev,   // c plane 1 (diag 61)
               const float* __restrict__ bg,
               const float* __restrict__ lns,
               const float* __restrict__ lnb,
               unsigned* __restrict__ outp) {
    __shared__ float red[8];
    const int u = threadIdx.x;
    const int b0 = blockIdx.x * 4;
    const int lane = u & 63, wid = u >> 6;
    const int kh = u >> 4, el = u & 7;

    for (int bl = 0; bl < 4; ++bl) {
        const int b = b0 + bl;
        const float* grow = gate0 + ((size_t)31 * kB + b) * kG5;
        const float fc = grow[u] + bg[u];
        const float fr = grow[kH + u] + bg[kH + u];
        const float ig = grow[2 * kH + u] + bg[2 * kH + u];
        const float og = grow[3 * kH + u] + bg[3 * kH + u];
        const float gg = grow[4 * kH + u] + bg[4 * kH + u];
        const float cl = cprev[((size_t)31 * kB + b) * kH + u];
        const float cu = cprev[((size_t)30 * kB + b) * kH + u];
        const float cv = sigm(fc) * cl + sigm(fr) * cu + sigm(ig) * tanhf(gg);

        float s = cv, s2 = cv * cv;
        #pragma unroll
        for (int off = 32; off; off >>= 1) {
            s  += __shfl_down(s,  off, 64);
            s2 += __shfl_down(s2, off, 64);
        }
        if (lane == 0) { red[wid] = s; red[4 + wid] = s2; }
        __syncthreads();
        const float sum = red[0] + red[1] + red[2] + red[3];
        const float sq  = red[4] + red[5] + red[6] + red[7];
        __syncthreads();
        const float mu   = sum * (1.f / kH);
        const float var  = sq * (1.f / kH) - mu * mu;
        const float rstd = rsqrtf(var + 1e-6f);
        const float hv   = sigm(og) * tanhf((cv - mu) * rstd * lns[u] + lnb[u]);
        unsigned short hb, lb;
        split1(hv, hb, lb);
        const size_t R = ((size_t)b * kM + 31) * kN + 31;
        const int t32 = (int)(R >> 5);
        const int lp = ((int)R & 31) + 32 * ((u >> 3) & 1);
        outp[(((size_t)t32 * 16 + kh) * 64 + lp) * 8 + el] =
            (unsigned)hb | ((unsigned)lb << 16);
    }
}

// ---------------------------------------------------------------------------
// Head GEMM over the out-overlay frag-packed h. Block's read byte range
// [t32*32768,..) == its write rows [64*bid, +64) -> self-contained in-place
// with one __syncthreads(). (round-8 verified layout; + sync for overlay)
// ---------------------------------------------------------------------------
__global__ __launch_bounds__(256)
void head_hpk(const unsigned short* __restrict__ whh,
              const unsigned short* __restrict__ whl,
              const float* __restrict__ bh,
              float* out) {
    const int tid = threadIdx.x;
    const int lane = tid & 63, w = tid >> 6;
    const int ln31 = lane & 31, ln5 = lane >> 5;
    const int r0 = blockIdx.x * 64;
    const int mt = w & 1, ng = w >> 1;
    const int t32 = blockIdx.x * 2 + mt;
    const unsigned* hpk = (const unsigned*)out;

    f32x16 acc[4];
    #pragma unroll
    for (int t = 0; t < 4; ++t)
        #pragma unroll
        for (int r = 0; r < 16; ++r) acc[t][r] = 0.f;

    const unsigned* ap = hpk + ((size_t)t32 * 1024 + lane) * 8;

    #pragma unroll 2
    for (int kc = 0; kc < 16; ++kc) {
        const uint4 p0 = *(const uint4*)(ap + (size_t)kc * 512);
        const uint4 p1 = *(const uint4*)(ap + (size_t)kc * 512 + 4);
        unsigned short h8[8], l8[8];
        h8[0] = (unsigned short)(p0.x & 0xffffu); l8[0] = (unsigned short)(p0.x >> 16);
        h8[1] = (unsigned short)(p0.y & 0xffffu); l8[1] = (unsigned short)(p0.y >> 16);
        h8[2] = (unsigned short)(p0.z & 0xffffu); l8[2] = (unsigned short)(p0.z >> 16);
        h8[3] = (unsigned short)(p0.w & 0xffffu); l8[3] = (unsigned short)(p0.w >> 16);
        h8[4] = (unsigned short)(p1.x & 0xffffu); l8[4] = (unsigned short)(p1.x >> 16);
        h8[5] = (unsigned short)(p1.y & 0xffffu); l8[5] = (unsigned short)(p1.y >> 16);
        h8[6] = (unsigned short)(p1.z & 0xffffu); l8[6] = (unsigned short)(p1.z >> 16);
        h8[7] = (unsigned short)(p1.w & 0xffffu); l8[7] = (unsigned short)(p1.w >> 16);
        const bf16x8 ah = *(const bf16x8*)h8;
        const bf16x8 al = *(const bf16x8*)l8;
        #pragma unroll
        for (int t = 0; t < 4; ++t) {
            const int nt = ng * 4 + t;
            const size_t g = ((size_t)(nt * 16 + kc) * 64 + lane) * 8;
            const bf16x8 wh = *(const bf16x8*)(whh + g);
            const bf16x8 wl = *(const bf16x8*)(whl + g);
            acc[t] = __builtin_amdgcn_mfma_f32_32x32x16_bf16(ah, wh, acc[t], 0, 0, 0);
            acc[t] = __builtin_amdgcn_mfma_f32_32x32x16_bf16(ah, wl, acc[t], 0, 0, 0);
            acc[t] = __builtin_amdgcn_mfma_f32_32x32x16_bf16(al, wh, acc[t], 0, 0, 0);
        }
    }

    __syncthreads();   // all overlay reads done before in-place stores

    #pragma unroll
    for (int t = 0; t < 4; ++t) {
        const int col = (ng * 4 + t) * 32 + ln31;
        const float bb = bh[col];
        #pragma unroll
        for (int r = 0; r < 16; ++r) {
            const int row = r0 + mt * 32 + (r & 3) + 8 * (r >> 2) + 4 * ln5;
            out[(size_t)row * kD + col] = acc[t][r] + bb;
        }
    }
}

// ---------------------------------------------------------------------------
// Fallback path (ws too small for fused layout): round-1/6 verified kernels.
// ---------------------------------------------------------------------------
__global__ __launch_bounds__(256)
void gate_mfma_legacy(int d,
               const float* __restrict__ x,
               const unsigned short* __restrict__ whi,
               const unsigned short* __restrict__ wlo,
               const unsigned short* __restrict__ hfh,
               const unsigned short* __restrict__ hfl,
               const unsigned short* __restrict__ h0fh,
               const unsigned short* __restrict__ h0fl,
               float* __restrict__ gates) {
    const int tid = threadIdx.x;
    const int ilo = max(0, d - (kN - 1));
    const int cell = blockIdx.x / 20;
    const int nc   = blockIdx.x % 20;
    const int i = ilo + cell;
    const int j = d - i;
    const int w = tid >> 6, lane = tid & 63;
    const int ln31 = lane & 31, ln5 = lane >> 5;
    const int mt = w & 1;
    const int ntile = nc * 2 + (w >> 1);
    const int hp = (d + 1) & 1;

    f32x16 acc;
    #pragma unroll
    for (int r = 0; r < 16; ++r) acc[r] = 0.f;

    const unsigned short* wph = whi + ((size_t)ntile * 3072 + lane) * 8;
    const unsigned short* wpl = wlo + ((size_t)ntile * 3072 + lane) * 8;

    const int b = mt * 32 + ln31;
    const float* xr = x + (((size_t)b * kM + i) * kN + j) * kD + ln5 * 8;
    #pragma unroll 4
    for (int kh = 0; kh < 16; ++kh) {
        const float4 v0 = *(const float4*)(xr + kh * 16);
        const float4 v1 = *(const float4*)(xr + kh * 16 + 4);
        unsigned short h8[8], l8[8];
        split1(v0.x, h8[0], l8[0]); split1(v0.y, h8[1], l8[1]);
        split1(v0.z, h8[2], l8[2]); split1(v0.w, h8[3], l8[3]);
        split1(v1.x, h8[4], l8[4]); split1(v1.y, h8[5], l8[5]);
        split1(v1.z, h8[6], l8[6]); split1(v1.w, h8[7], l8[7]);
        const bf16x8 ah = *(const bf16x8*)h8;
        const bf16x8 al = *(const bf16x8*)l8;
        const bf16x8 wh = *(const bf16x8*)(wph + (size_t)kh * 512);
        const bf16x8 wl = *(const bf16x8*)(wpl + (size_t)kh * 512);
        acc = __builtin_amdgcn_mfma_f32_32x32x16_bf16(ah, wh, acc, 0, 0, 0);
        acc = __builtin_amdgcn_mfma_f32_32x32x16_bf16(ah, wl, acc, 0, 0, 0);
        acc = __builtin_amdgcn_mfma_f32_32x32x16_bf16(al, wh, acc, 0, 0, 0);
    }

    const unsigned short *plh, *pll, *puh, *pul;
    if (j > 0) {
        const size_t o = ((size_t)(hp * kM + i)) * 16384 + ((size_t)(mt * 16) * 64 + lane) * 8;
        plh = hfh + o; pll = hfl + o;
    } else {
        plh = h0fh + lane * 8; pll = h0fl + lane * 8;
    }
    if (i > 0) {
        const size_t o = ((size_t)(hp * kM + (i - 1))) * 16384 + ((size_t)(mt * 16) * 64 + lane) * 8;
        puh = hfh + o; pul = hfl + o;
    } else {
        puh = h0fh + lane * 8; pul = h0fl + lane * 8;
    }

    #pragma unroll 4
    for (int kh = 0; kh < 16; ++kh) {
        const bf16x8 ah = *(const bf16x8*)(plh + (size_t)kh * 512);
        const bf16x8 al = *(const bf16x8*)(pll + (size_t)kh * 512);
        const bf16x8 wh = *(const bf16x8*)(wph + (size_t)(16 + kh) * 512);
        const bf16x8 wl = *(const bf16x8*)(wpl + (size_t)(16 + kh) * 512);
        acc = __builtin_amdgcn_mfma_f32_32x32x16_bf16(ah, wh, acc, 0, 0, 0);
        acc = __builtin_amdgcn_mfma_f32_32x32x16_bf16(ah, wl, acc, 0, 0, 0);
        acc = __builtin_amdgcn_mfma_f32_32x32x16_bf16(al, wh, acc, 0, 0, 0);
    }
    #pragma unroll 4
    for (int kh = 0; kh < 16; ++kh) {
        const bf16x8 ah = *(const bf16x8*)(puh + (size_t)kh * 512);
        const bf16x8 al = *(const bf16x8*)(pul + (size_t)kh * 512);
        const bf16x8 wh = *(const bf16x8*)(wph + (size_t)(32 + kh) * 512);
        const bf16x8 wl = *(const bf16x8*)(wpl + (size_t)(32 + kh) * 512);
        acc = __builtin_amdgcn_mfma_f32_32x32x16_bf16(ah, wh, acc, 0, 0, 0);
        acc = __builtin_amdgcn_mfma_f32_32x32x16_bf16(ah, wl, acc, 0, 0, 0);
        acc = __builtin_amdgcn_mfma_f32_32x32x16_bf16(al, wh, acc, 0, 0, 0);
    }

    const int col = ntile * 32 + ln31;
    #pragma unroll
    for (int r = 0; r < 16; ++r) {
        const int mrow = (r & 3) + 8 * (r >> 2) + 4 * ln5;
        const int bb = mt * 32 + mrow;
        gates[((size_t)i * kB + bb) * kG5 + col] = acc[r];
    }
}

__global__ __launch_bounds__(256)
void cell_legacy(int d,
             const float* __restrict__ bg,
             const float* __restrict__ lns,
             const float* __restrict__ lnb,
             const float* __restrict__ gates,
             float* __restrict__ c_bufs,
             unsigned short* __restrict__ hfh,
             unsigned short* __restrict__ hfl,
             float* out) {
    __shared__ float red[8];
    const int tid = threadIdx.x;
    const int ilo = max(0, d - (kN - 1));
    const int i = ilo + (blockIdx.x >> 4);
    const int j = d - i;
    const int b0 = (blockIdx.x & 15) * 4;
    const int plane = kM * kB * kH;
    const float* c_prev = c_bufs + ((d + 1) & 1) * plane;
    float*       c_cur  = c_bufs + (d & 1) * plane;
    const int hp = d & 1;
    unsigned* outp = (unsigned*)out;

    const int u = tid;
    const float bg0 = bg[u];
    const float bg1 = bg[kH + u];
    const float bg2 = bg[2 * kH + u];
    const float bg3 = bg[3 * kH + u];
    const float bg4 = bg[4 * kH + u];
    const float lnsc = lns[u];
    const float lnbi = lnb[u];
    const int lane = tid & 63, wid = tid >> 6;
    const int kh = u >> 4, r = u & 15, jj = r & 7;

    for (int bl = 0; bl < 4; ++bl) {
        const int b = b0 + bl;
        const float* grow = gates + ((size_t)i * kB + b) * kG5;
        const float fc = grow[u] + bg0;
        const float fr = grow[kH + u] + bg1;
        const float ig = grow[2 * kH + u] + bg2;
        const float og = grow[3 * kH + u] + bg3;
        const float gg = grow[4 * kH + u] + bg4;
        const float cl = (j > 0) ? c_prev[((size_t)i * kB + b) * kH + u] : 0.f;
        const float cu = (i > 0) ? c_prev[((size_t)(i - 1) * kB + b) * kH + u] : 0.f;

        const float cell_v = sigm(fc) * cl + sigm(fr) * cu + sigm(ig) * tanhf(gg);
        c_cur[((size_t)i * kB + b) * kH + u] = cell_v;

        float s = cell_v, s2 = cell_v * cell_v;
        #pragma unroll
        for (int off = 32; off; off >>= 1) {
            s  += __shfl_down(s,  off, 64);
            s2 += __shfl_down(s2, off, 64);
        }
        if (lane == 0) { red[wid] = s; red[4 + wid] = s2; }
        __syncthreads();
        const float sum = red[0] + red[1] + red[2] + red[3];
        const float sq  = red[4] + red[5] + red[6] + red[7];
        __syncthreads();

        const float mu   = sum * (1.f / kH);
        const float var  = sq * (1.f / kH) - mu * mu;
        const float rstd = rsqrtf(var + 1e-6f);
        const float hv   = sigm(og) * tanhf((cell_v - mu) * rstd * lnsc + lnbi);

        unsigned short hb, lb;
        split1(hv, hb, lb);
        const int mt2 = b >> 5;
        const int fl = (b & 31) + 32 * (r >> 3);
        const size_t fo = ((size_t)(hp * kM + i)) * 16384
                        + (((size_t)(mt2 * 16 + kh) * 64 + fl) * 8 + jj);
        hfh[fo] = hb; hfl[fo] = lb;
        outp[(((size_t)b * kM + i) * kN + j) * kD + u] = (unsigned)hb | ((unsigned)lb << 16);
    }
}

__global__ __launch_bounds__(256)
void head_mfma64(const unsigned short* __restrict__ whh,
                 const unsigned short* __restrict__ whl,
                 const float* __restrict__ bh,
                 float* out) {
    const int tid = threadIdx.x;
    const int lane = tid & 63, w = tid >> 6;
    const int ln31 = lane & 31, ln5 = lane >> 5;
    const int r0 = blockIdx.x * 64;
    const int mt = w & 1, ng = w >> 1;
    unsigned* outp = (unsigned*)out;

    f32x16 acc[4];
    #pragma unroll
    for (int t = 0; t < 4; ++t)
        #pragma unroll
        for (int r = 0; r < 16; ++r) acc[t][r] = 0.f;

    const int m = r0 + mt * 32 + ln31;
    const unsigned* arow = outp + (size_t)m * kD + ln5 * 8;

    #pragma unroll 2
    for (int kc = 0; kc < 16; ++kc) {
        const uint4 p0 = *(const uint4*)(arow + kc * 16);
        const uint4 p1 = *(const uint4*)(arow + kc * 16 + 4);
        unsigned short h8[8], l8[8];
        h8[0] = (unsigned short)(p0.x & 0xffffu); l8[0] = (unsigned short)(p0.x >> 16);
        h8[1] = (unsigned short)(p0.y & 0xffffu); l8[1] = (unsigned short)(p0.y >> 16);
        h8[2] = (unsigned short)(p0.z & 0xffffu); l8[2] = (unsigned short)(p0.z >> 16);
        h8[3] = (unsigned short)(p0.w & 0xffffu); l8[3] = (unsigned short)(p0.w >> 16);
        h8[4] = (unsigned short)(p1.x & 0xffffu); l8[4] = (unsigned short)(p1.x >> 16);
        h8[5] = (unsigned short)(p1.y & 0xffffu); l8[5] = (unsigned short)(p1.y >> 16);
        h8[6] = (unsigned short)(p1.z & 0xffffu); l8[6] = (unsigned short)(p1.z >> 16);
        h8[7] = (unsigned short)(p1.w & 0xffffu); l8[7] = (unsigned short)(p1.w >> 16);
        const bf16x8 ah = *(const bf16x8*)h8;
        const bf16x8 al = *(const bf16x8*)l8;
        #pragma unroll
        for (int t = 0; t < 4; ++t) {
            const int nt = ng * 4 + t;
            const size_t g = ((size_t)(nt * 16 + kc) * 64 + lane) * 8;
            const bf16x8 wh = *(const bf16x8*)(whh + g);
            const bf16x8 wl = *(const bf16x8*)(whl + g);
            acc[t] = __builtin_amdgcn_mfma_f32_32x32x16_bf16(ah, wh, acc[t], 0, 0, 0);
            acc[t] = __builtin_amdgcn_mfma_f32_32x32x16_bf16(ah, wl, acc[t], 0, 0, 0);
            acc[t] = __builtin_amdgcn_mfma_f32_32x32x16_bf16(al, wh, acc[t], 0, 0, 0);
        }
    }

    __syncthreads();

    #pragma unroll
    for (int t = 0; t < 4; ++t) {
        const int col = (ng * 4 + t) * 32 + ln31;
        const float bb = bh[col];
        #pragma unroll
        for (int r = 0; r < 16; ++r) {
            const int row = r0 + mt * 32 + (r & 3) + 8 * (r >> 2) + 4 * ln5;
            out[(size_t)row * kD + col] = acc[t][r] + bb;
        }
    }
}

extern "C" void kernel_launch(void* const* d_in, const int* in_sizes, int n_in,
                              void* d_out, int out_size, void* d_ws, size_t ws_size,
                              hipStream_t stream) {
    const float* x     = (const float*)d_in[0];
    const float* Wg    = (const float*)d_in[1];
    const float* bg    = (const float*)d_in[2];
    const float* lns   = (const float*)d_in[3];
    const float* lnb   = (const float*)d_in[4];
    const float* Wh    = (const float*)d_in[5];
    const float* bh    = (const float*)d_in[6];
    const float* hinit = (const float*)d_in[7];
    float* out = (float*)d_out;

    // ws layout (byte offsets, all 16B-aligned)
    char* wsb = (char*)d_ws;
    float*          gates  = (float*)(wsb);                    // 2 x 10,485,760
    float*          c_bufs = (float*)(wsb + 20971520);         // 2 x  2,097,152
    unsigned short* whi    = (unsigned short*)(wsb + 25165824);//  1,966,080
    unsigned short* wlo    = (unsigned short*)(wsb + 27131904);//  1,966,080
    unsigned short* h0fh   = (unsigned short*)(wsb + 29097984);//     16,384
    unsigned short* h0fl   = (unsigned short*)(wsb + 29114368);//     16,384
    unsigned short* whh    = (unsigned short*)(wsb + 29130752);//    131,072
    unsigned short* whl    = (unsigned short*)(wsb + 29261824);//    131,072
    unsigned short* xfh    = (unsigned short*)(wsb + 29392896);// 33,554,432
    unsigned short* xfl    = (unsigned short*)(wsb + 62947328);// 33,554,432
    // fallback-only (reuses xf region; fallback never touches xf):
    unsigned short* hfh    = (unsigned short*)(wsb + 29392896);//  2,097,152
    unsigned short* hfl    = (unsigned short*)(wsb + 31490048);//  2,097,152
    const size_t kWsFused = 96501760;                          // end of xfl

    const bool fused = (ws_size >= kWsFused);

    hipLaunchKernelGGL(prep_w,   dim3(480), dim3(256), 0, stream, Wg, whi, wlo);
    hipLaunchKernelGGL(prep_wh,  dim3(32),  dim3(256), 0, stream, Wh, whh, whl);
    hipLaunchKernelGGL(prep_h0f, dim3(4),   dim3(256), 0, stream, hinit, h0fh, h0fl);

    if (fused) {
        hipLaunchKernelGGL(prep_x, dim3(8192), dim3(256), 0, stream, x, xfh, xfl);
        for (int d = 0; d < kM + kN - 1; ++d) {
            const int ilo = max(0, d - (kN - 1));
            const int ihi = min(d, kM - 1);
            const int ncell = ihi - ilo + 1;
            hipLaunchKernelGGL(gate_fused, dim3(ncell * 20), dim3(256), 0, stream,
                               d, xfh, xfl, whi, wlo, h0fh, h0fl,
                               gates + ((size_t)((d + 1) & 1)) * kGP,
                               gates + ((size_t)(d & 1)) * kGP,
                               c_bufs + ((size_t)(d & 1)) * kCP,
                               c_bufs + ((size_t)((d + 1) & 1)) * kCP,
                               bg, lns, lnb, (unsigned*)out);
        }
        // cells of diag 62 (gates plane 62&1=0; c of diag 61 in plane 1)
        hipLaunchKernelGGL(cell_tail, dim3(16), dim3(256), 0, stream,
                           gates, c_bufs + (size_t)kCP, bg, lns, lnb, (unsigned*)out);
        hipLaunchKernelGGL(head_hpk, dim3(1024), dim3(256), 0, stream, whh, whl, bh, out);
    } else {
        for (int d = 0; d < kM + kN - 1; ++d) {
            const int ilo = max(0, d - (kN - 1));
            const int ihi = min(d, kM - 1);
            const int ncell = ihi - ilo + 1;
            hipLaunchKernelGGL(gate_mfma_legacy, dim3(ncell * 20), dim3(256), 0, stream,
                               d, x, whi, wlo, hfh, hfl, h0fh, h0fl, gates);
            hipLaunchKernelGGL(cell_legacy, dim3(ncell * 16), dim3(256), 0, stream,
                               d, bg, lns, lnb, gates, c_bufs, hfh, hfl, out);
        }
        hipLaunchKernelGGL(head_mfma64, dim3(1024), dim3(256), 0, stream, whh, whl, bh, out);
    }
}